// Round 10
// baseline (64.001 us; speedup 1.0000x reference)
//
#include <hip/hip_runtime.h>
#include <hip/hip_bf16.h>
#include <stdint.h>

// SimCLR loss, n=8192, d=128, T=0.07.
// R10 = R9 (fine-grain symmetric triangle, LDS-staged B) with the atomics
// hoisted OUT of the barrier loop. R9 lesson: __syncthreads drains vmcnt(0),
// which included the in-loop col-sum atomicAdds (~900cy HBM write-through
// round trips, WRITE_SIZE showed 64B/atomic) -> every phase ate the atomic
// latency. Col sums now accumulate in 8 registers (static idx) and all
// atomics fire after the loop. Stage(0) issued before A-gather (prologue
// overlap). 3 dispatches (finalize does the mean via atomicAdd).
//  k_normalize: fp32 -> row-L2-normalized bf16 fn; blk0 zeroes E and out
//  k_simexp:    triangle band blocks -> atomicAdd into E[8192] (end only)
//  k_finalize:  per-row term -> block partial -> atomicAdd(out, partial/N)

#define N_ROWS 8192
#define DIM    128
#define HALF_N 4096
#define NBANDS 64
#define BROWS  128                           // band width
#define NTRI   (NBANDS * (NBANDS + 1) / 2)   // 2080 blocks
#define CHUNK  64                            // staged cols per chunk (16 KiB)
#define NCH    (BROWS / CHUNK)               // 2 chunks per block
#define NJT    (CHUNK / 16)                  // 4 j-tiles per chunk

static constexpr float INV_T = 14.285714285714286f;   // 1/0.07
static constexpr float SCALE = 20.60992915555662f;    // log2(e)/0.07

typedef __attribute__((ext_vector_type(8))) short short8;   // 8 bf16 = 4 VGPR
typedef __attribute__((ext_vector_type(4))) float f32x4;

#if __has_builtin(__builtin_amdgcn_exp2f)
__device__ inline float fast_exp2(float x) { return __builtin_amdgcn_exp2f(x); }
#else
__device__ inline float fast_exp2(float x) { return exp2f(x); }
#endif

__device__ inline float bf_lo(uint32_t u) { return __uint_as_float(u << 16); }
__device__ inline float bf_hi(uint32_t u) { return __uint_as_float(u & 0xFFFF0000u); }
__device__ inline uint16_t f2bf(float x) {
    uint32_t u = __float_as_uint(x);
    return (uint16_t)((u + 0x7FFFu + ((u >> 16) & 1u)) >> 16);   // RNE
}

// async global->LDS, 16B/lane; LDS dest = wave-uniform base + lane*16 (HW)
__device__ inline void load_lds16(const void* g, void* l) {
    __builtin_amdgcn_global_load_lds(
        (const __attribute__((address_space(1))) uint32_t*)g,
        (__attribute__((address_space(3))) uint32_t*)l, 16, 0, 0);
}

// ---------------- kernel 1: row L2-normalize; zero E and out --------------
__global__ __launch_bounds__(256) void k_normalize(const float* __restrict__ f,
                                                   uint16_t* __restrict__ fn,
                                                   float* __restrict__ E,
                                                   float* __restrict__ out) {
    if (blockIdx.x == 0) {               // zero E (completes before k_simexp)
        if (threadIdx.x == 0) out[0] = 0.0f;
        float4 z = {0.f, 0.f, 0.f, 0.f};
        #pragma unroll
        for (int i = 0; i < 8; ++i)
            ((float4*)E)[threadIdx.x + i * 256] = z;
    }
    int wid  = (blockIdx.x * blockDim.x + threadIdx.x) >> 6;   // one wave per row
    int lane = threadIdx.x & 63;
    const float2* src = (const float2*)(f + (size_t)wid * DIM);
    float2 v = src[lane];
    float ss = v.x * v.x + v.y * v.y;
    #pragma unroll
    for (int m = 1; m < 64; m <<= 1) ss += __shfl_xor(ss, m, 64);
    float inv = rsqrtf(ss);
    ushort2 o;
    o.x = f2bf(v.x * inv);
    o.y = f2bf(v.y * inv);
    ((ushort2*)(fn + (size_t)wid * DIM))[lane] = o;
}

// ---------------- kernel 2: triangle sim + exp-sum (MFMA, LDS-staged) -----
// LDS chunk: col cc (0..63) at bytes cc*256; 16B slot pc holds logical
// k-chunk pc ^ (cc&7)  (bank-spread; validated R7).
__global__ __launch_bounds__(256) void k_simexp(const uint16_t* __restrict__ fn,
                                                float* __restrict__ E) {
    __shared__ __align__(16) uint16_t Bl[2][CHUNK * DIM];   // 2 x 16 KiB
    // decode triangular block index (scalar loop, <=64 iters, SALU)
    int bx = 0, rem = blockIdx.x;
    while (rem >= NBANDS - bx) { rem -= NBANDS - bx; ++bx; }
    const int by = bx + rem;
    const bool diag = (by == bx);

    const int tid  = threadIdx.x;
    const int lane = tid & 63;
    const int w    = tid >> 6;
    const int ib   = bx * BROWS + w * 32;
    const int jb   = by * BROWS;
    const int lr = lane & 15;
    const int lk = lane >> 4;

    const short8* fn8 = (const short8*)fn;

    // staging: wave w covers chunk cols w*16..+15; 4 instrs x 64 lanes x 16B
    const int scc0 = w * 16 + (lane >> 4);
    #define STAGE(c, buf)                                                     \
        _Pragma("unroll")                                                     \
        for (int i = 0; i < 4; ++i) {                                         \
            int cc = scc0 + i * 4;                                            \
            int lc = (lane & 15) ^ (cc & 7);                                  \
            load_lds16(fn8 + (size_t)(jb + (c) * CHUNK + cc) * 16 + lc,       \
                       &Bl[buf][w * 2048 + i * 512]);                         \
        }

    STAGE(0, 0)   // issue DMA first; latency hides under A-gather below

    // A fragments: row ib+mt*16+lr, dims kc*32+lk*8..+8  (32 VGPR)
    short8 Af[2][4];
    #pragma unroll
    for (int mt = 0; mt < 2; ++mt)
        #pragma unroll
        for (int kc = 0; kc < 4; ++kc)
            Af[mt][kc] = fn8[(size_t)(ib + mt * 16 + lr) * 16 + kc * 4 + lk];

    float es[2][4];                       // row accumulators
    #pragma unroll
    for (int mt = 0; mt < 2; ++mt)
        #pragma unroll
        for (int r = 0; r < 4; ++r) es[mt][r] = 0.0f;
    float cs_acc[NCH][NJT];               // col accumulators (static idx)
    #pragma unroll
    for (int c = 0; c < NCH; ++c)
        #pragma unroll
        for (int jt = 0; jt < NJT; ++jt) cs_acc[c][jt] = 0.0f;

    #pragma unroll
    for (int c = 0; c < NCH; ++c) {
        __syncthreads();                   // stage(c) drained & visible
        if (c + 1 < NCH) {
            STAGE(c + 1, (c + 1) & 1)      // DMA overlaps compute(c)
        }
        const char* bp = (const char*)&Bl[c & 1][0];
        #pragma unroll
        for (int jt = 0; jt < NJT; ++jt) {
            const int rbase = (jt * 16 + lr) * 256;
            short8 Bf[4];
            #pragma unroll
            for (int kc = 0; kc < 4; ++kc)
                Bf[kc] = *(const short8*)(bp + rbase + ((((kc << 2) | lk) ^ (lr & 7)) << 4));
            float cs = 0.0f;
            #pragma unroll
            for (int mt = 0; mt < 2; ++mt) {
                f32x4 acc = {0.0f, 0.0f, 0.0f, 0.0f};
                #pragma unroll
                for (int kc = 0; kc < 4; ++kc)
                    acc = __builtin_amdgcn_mfma_f32_16x16x32_bf16(Af[mt][kc], Bf[kc], acc, 0, 0, 0);
                #pragma unroll
                for (int r = 0; r < 4; ++r) {
                    float e = fast_exp2(fmaf(acc[r], SCALE, -SCALE));
                    es[mt][r] += e;       // row accumulator
                    cs += e;              // col partial (this wave's rows)
                }
            }
            cs_acc[c][jt] += cs;          // register, NO atomic in the loop
        }
    }

    // epilogue: all reductions + atomics AFTER the barrier loop.
    if (!diag) {
        #pragma unroll
        for (int c = 0; c < NCH; ++c)
            #pragma unroll
            for (int jt = 0; jt < NJT; ++jt) {
                float cs = cs_acc[c][jt];
                cs += __shfl_xor(cs, 16, 64);
                cs += __shfl_xor(cs, 32, 64);
                if (lk == 0)
                    atomicAdd(&E[jb + c * CHUNK + jt * 16 + lr], cs);
            }
    }
    #pragma unroll
    for (int mt = 0; mt < 2; ++mt)
        #pragma unroll
        for (int r = 0; r < 4; ++r) {
            float v = es[mt][r];
            v += __shfl_xor(v, 1, 64);
            v += __shfl_xor(v, 2, 64);
            v += __shfl_xor(v, 4, 64);
            v += __shfl_xor(v, 8, 64);
            if (lr == 0)
                atomicAdd(&E[ib + mt * 16 + lk * 4 + r], v);
        }
}

// ---------------- kernel 3: finalize + mean (atomic) ----------------------
__global__ __launch_bounds__(256) void k_finalize(const uint16_t* __restrict__ fn,
                                                  const float* __restrict__ E,
                                                  float* __restrict__ out) {
    __shared__ float sm[4];
    int wid  = (blockIdx.x * blockDim.x + threadIdx.x) >> 6;   // one wave per row
    int lane = threadIdx.x & 63;
    int partner = (wid + HALF_N) & (N_ROWS - 1);
    const uint32_t* fr = (const uint32_t*)(fn + (size_t)wid * DIM);
    const uint32_t* pr = (const uint32_t*)(fn + (size_t)partner * DIM);
    uint32_t a = fr[lane], p = pr[lane];
    float a0 = bf_lo(a), a1 = bf_hi(a);
    float p0 = bf_lo(p), p1 = bf_hi(p);
    float sd = a0 * a0 + a1 * a1;       // self dot (diagonal recompute)
    float pd = a0 * p0 + a1 * p1;       // positive-pair dot
    #pragma unroll
    for (int m = 1; m < 64; m <<= 1) {
        sd += __shfl_xor(sd, m, 64);
        pd += __shfl_xor(pd, m, 64);
    }
    if (lane == 0) {
        float ep = E[wid] - fast_exp2(fmaf(sd, SCALE, -SCALE));   // drop diag
        sm[threadIdx.x >> 6] = INV_T + logf(ep) - pd * INV_T;
    }
    __syncthreads();
    if (threadIdx.x == 0)
        atomicAdd(out, (sm[0] + sm[1] + sm[2] + sm[3]) * (1.0f / N_ROWS));
}

extern "C" void kernel_launch(void* const* d_in, const int* in_sizes, int n_in,
                              void* d_out, int out_size, void* d_ws, size_t ws_size,
                              hipStream_t stream) {
    const float* feat = (const float*)d_in[0];
    float* out = (float*)d_out;

    // ws: fn (bf16, 2 MiB) | E (f32, 32 KiB)
    uint16_t* fn = (uint16_t*)d_ws;
    float* E     = (float*)((char*)d_ws + (size_t)N_ROWS * DIM * 2);

    k_normalize<<<dim3(N_ROWS / 4), dim3(256), 0, stream>>>(feat, fn, E, out);
    k_simexp<<<dim3(NTRI), dim3(256), 0, stream>>>(fn, E);
    k_finalize<<<dim3(N_ROWS / 4), dim3(256), 0, stream>>>(fn, E, out);
}

// Round 11
// 38.691 us; speedup vs baseline: 1.6542x; 1.6542x over previous
//
#include <hip/hip_runtime.h>
#include <hip/hip_bf16.h>
#include <stdint.h>

// SimCLR loss, n=8192, d=128, T=0.07.
// R11: fragment-major pre-layout kills the staging problem entirely.
// R1-R6 bottleneck: B-fragment gathers = 16 cache lines/instr (stride-256B,
// 64B useful per line). R7-R10 fixed lines via LDS but bought barrier/DMA
// serialization + prologue-dominated blocks (~26us invariant). Now
// k_normalize writes fnB in MFMA-fragment order: fragment (tile,kc) =
// 1 KB contiguous, loaded by ONE coalesced global_load_dwordx4 per lane
// (fnB16[tile*256 + kc*64 + lane]). A uses the same layout. k_simexp has
// NO LDS, NO barriers, NO atomics - pure load/MFMA/exp2 stream, 4 w/SIMD.
//  k_normalize: fp32 -> bf16: fn (row-major, for finalize) + fnB (frag-major)
//  k_simexp:    E_part[row][slice] = sum_j exp2((dot-1)*s)   (plain stores)
//  k_finalize:  per-row term -> terms[];  k_reduce: mean -> out[0]

#define N_ROWS 8192
#define DIM    128
#define HALF_N 4096
#define N_SLICES 32
#define NT 16                     // 16-col tiles per 256-col slice
#define ROWS_PER_BLOCK 256        // 4 waves x 64 rows

static constexpr float INV_T = 14.285714285714286f;   // 1/0.07
static constexpr float SCALE = 20.60992915555662f;    // log2(e)/0.07

typedef __attribute__((ext_vector_type(8))) short short8;   // 8 bf16 = 4 VGPR
typedef __attribute__((ext_vector_type(4))) float f32x4;

#if __has_builtin(__builtin_amdgcn_exp2f)
__device__ inline float fast_exp2(float x) { return __builtin_amdgcn_exp2f(x); }
#else
__device__ inline float fast_exp2(float x) { return exp2f(x); }
#endif

__device__ inline float bf_lo(uint32_t u) { return __uint_as_float(u << 16); }
__device__ inline float bf_hi(uint32_t u) { return __uint_as_float(u & 0xFFFF0000u); }
__device__ inline uint16_t f2bf(float x) {
    uint32_t u = __float_as_uint(x);
    return (uint16_t)((u + 0x7FFFu + ((u >> 16) & 1u)) >> 16);   // RNE
}

// fnB chunk layout (16B units): chunk(j,k) = (j>>4)*256 + (k>>5)*64
//   + ((k>>3)&3)*16 + (j&15); byte-in-chunk = (k&7)*2.
// => fragment load for lane l: fnB16[tile*256 + kc*64 + l] holds
//    row tile*16+(l&15), dims kc*32+(l>>4)*8 .. +8.   (A and B identical)

// ---------------- kernel 1: normalize -> fn (row-major) + fnB (frag) ------
__global__ __launch_bounds__(256) void k_normalize(const float* __restrict__ f,
                                                   uint16_t* __restrict__ fn,
                                                   uint16_t* __restrict__ fnB) {
    int wid  = (blockIdx.x * blockDim.x + threadIdx.x) >> 6;   // one wave per row
    int lane = threadIdx.x & 63;
    const float2* src = (const float2*)(f + (size_t)wid * DIM);
    float2 v = src[lane];
    float ss = v.x * v.x + v.y * v.y;
    #pragma unroll
    for (int m = 1; m < 64; m <<= 1) ss += __shfl_xor(ss, m, 64);
    float inv = rsqrtf(ss);
    ushort2 o;
    o.x = f2bf(v.x * inv);
    o.y = f2bf(v.y * inv);
    ((ushort2*)(fn + (size_t)wid * DIM))[lane] = o;              // row-major
    int k0 = lane * 2;                                            // frag-major
    size_t chunk = (size_t)(wid >> 4) * 256 + (k0 >> 5) * 64 +
                   ((k0 >> 3) & 3) * 16 + (wid & 15);
    *(ushort2*)((char*)fnB + chunk * 16 + (k0 & 7) * 2) = o;
}

// ---------------- kernel 2: sim + exp-sum, fragment-major loads -----------
// Grid (32, 32): block = 4 waves x 64 rows = 256 rows, 256 cols (16 tiles).
__global__ __launch_bounds__(256) void k_simexp(const uint16_t* __restrict__ fnB,
                                                float* __restrict__ E_part) {
    const int lane  = threadIdx.x & 63;
    const int w     = threadIdx.x >> 6;
    const int ib    = blockIdx.x * ROWS_PER_BLOCK + w * 64;
    const int slice = blockIdx.y;
    const int lr = lane & 15;
    const int lk = lane >> 4;

    const short8* fnB8 = (const short8*)fnB;   // 16B chunks
    const int tileA0 = ib >> 4;
    const int jt0    = slice * NT;             // first B tile of this slice

    // A fragments: one coalesced 1KB load each (16 total, 64 regs)
    short8 Af[4][4];
    #pragma unroll
    for (int mt = 0; mt < 4; ++mt)
        #pragma unroll
        for (int kc = 0; kc < 4; ++kc)
            Af[mt][kc] = fnB8[(size_t)(tileA0 + mt) * 256 + kc * 64 + lane];

    float es[4][4];
    #pragma unroll
    for (int mt = 0; mt < 4; ++mt)
        #pragma unroll
        for (int r = 0; r < 4; ++r) es[mt][r] = 0.0f;

    for (int jt = 0; jt < NT; ++jt) {
        const short8* bp = fnB8 + (size_t)(jt0 + jt) * 256 + lane;
        short8 Bf[4];
        #pragma unroll
        for (int kc = 0; kc < 4; ++kc)
            Bf[kc] = bp[kc * 64];              // coalesced 1KB per load
        #pragma unroll
        for (int mt = 0; mt < 4; ++mt) {
            f32x4 acc = {0.0f, 0.0f, 0.0f, 0.0f};
            #pragma unroll
            for (int kc = 0; kc < 4; ++kc)
                acc = __builtin_amdgcn_mfma_f32_16x16x32_bf16(Af[mt][kc], Bf[kc], acc, 0, 0, 0);
            #pragma unroll
            for (int r = 0; r < 4; ++r)
                es[mt][r] += fast_exp2(fmaf(acc[r], SCALE, -SCALE));
        }
    }

    // C/D: col = lane&15 (= B row j), row = lk*4 + r. Reduce over col-lanes.
    #pragma unroll
    for (int mt = 0; mt < 4; ++mt)
        #pragma unroll
        for (int r = 0; r < 4; ++r) {
            float v = es[mt][r];
            v += __shfl_xor(v, 1, 64);
            v += __shfl_xor(v, 2, 64);
            v += __shfl_xor(v, 4, 64);
            v += __shfl_xor(v, 8, 64);
            if (lr == 0)
                E_part[(size_t)(ib + mt * 16 + lk * 4 + r) * N_SLICES + slice] = v;
        }
}

// ---------------- kernel 3: per-row finalize -> block partials ------------
__global__ __launch_bounds__(256) void k_finalize(const uint16_t* __restrict__ fn,
                                                  const float* __restrict__ E_part,
                                                  float* __restrict__ terms) {
    __shared__ float sm[4];
    int wid  = (blockIdx.x * blockDim.x + threadIdx.x) >> 6;   // one wave per row
    int lane = threadIdx.x & 63;
    int partner = (wid + HALF_N) & (N_ROWS - 1);
    const uint32_t* fr = (const uint32_t*)(fn + (size_t)wid * DIM);
    const uint32_t* pr = (const uint32_t*)(fn + (size_t)partner * DIM);
    uint32_t a = fr[lane], p = pr[lane];
    float a0 = bf_lo(a), a1 = bf_hi(a);
    float p0 = bf_lo(p), p1 = bf_hi(p);
    float sd = a0 * a0 + a1 * a1;       // self dot (diagonal recompute)
    float pd = a0 * p0 + a1 * p1;       // positive-pair dot
    #pragma unroll
    for (int m = 1; m < 64; m <<= 1) {
        sd += __shfl_xor(sd, m, 64);
        pd += __shfl_xor(pd, m, 64);
    }
    float e = (lane < N_SLICES) ? E_part[(size_t)wid * N_SLICES + lane] : 0.0f;
    #pragma unroll
    for (int m = 1; m < 64; m <<= 1) e += __shfl_xor(e, m, 64);
    if (lane == 0) {
        float ep = e - fast_exp2(fmaf(sd, SCALE, -SCALE));   // remove diagonal
        sm[threadIdx.x >> 6] = INV_T + logf(ep) - pd * INV_T;
    }
    __syncthreads();
    if (threadIdx.x == 0)
        terms[blockIdx.x] = sm[0] + sm[1] + sm[2] + sm[3];
}

// ---------------- kernel 4: mean over 2048 block partials ----------------
__global__ __launch_bounds__(256) void k_reduce(const float* __restrict__ terms,
                                                float* __restrict__ out) {
    __shared__ float sm[4];
    float acc = 0.0f;
    for (int i = threadIdx.x; i < N_ROWS / 4; i += 256) acc += terms[i];
    #pragma unroll
    for (int m = 1; m < 64; m <<= 1) acc += __shfl_xor(acc, m, 64);
    if ((threadIdx.x & 63) == 0) sm[threadIdx.x >> 6] = acc;
    __syncthreads();
    if (threadIdx.x == 0)
        out[0] = (sm[0] + sm[1] + sm[2] + sm[3]) * (1.0f / N_ROWS);
}

extern "C" void kernel_launch(void* const* d_in, const int* in_sizes, int n_in,
                              void* d_out, int out_size, void* d_ws, size_t ws_size,
                              hipStream_t stream) {
    const float* feat = (const float*)d_in[0];
    float* out = (float*)d_out;

    // ws: fn (2 MiB) | fnB (2 MiB) | E_part (1 MiB) | terms (8 KiB)
    uint16_t* fn  = (uint16_t*)d_ws;
    uint16_t* fnB = fn + (size_t)N_ROWS * DIM;
    float* E_part = (float*)(fnB + (size_t)N_ROWS * DIM);
    float* terms  = E_part + (size_t)N_ROWS * N_SLICES;

    k_normalize<<<dim3(N_ROWS / 4), dim3(256), 0, stream>>>(feat, fn, fnB);
    k_simexp<<<dim3(N_ROWS / ROWS_PER_BLOCK, N_SLICES), dim3(256), 0, stream>>>(fnB, E_part);
    k_finalize<<<dim3(N_ROWS / 4), dim3(256), 0, stream>>>(fn, E_part, terms);
    k_reduce<<<dim3(1), dim3(256), 0, stream>>>(terms, out);
}